// Round 14
// baseline (250.479 us; speedup 1.0000x reference)
//
#include <hip/hip_runtime.h>
#include <hip/hip_bf16.h>

// Problem constants (fixed by reference)
#define N_NODES   16384
#define DEG       16
#define EDGES     262144          // N_NODES*DEG
#define HC        256             // HEADS*OUT_C
#define KDIM      16384           // 64 nodes * 256 feat
#define NEG_SLOPE 0.2f

typedef __attribute__((ext_vector_type(8))) short short8;   // 8 bf16
typedef __attribute__((ext_vector_type(4))) float floatx4;

static __device__ __forceinline__ unsigned short f2bf(float f) {
    union { __hip_bfloat16 h; unsigned short u; } c;
    c.h = __float2bfloat16(f);          // RNE
    return c.u;
}
static __device__ __forceinline__ unsigned int packbf2(float lo, float hi) {
    union { __hip_bfloat162 h2; unsigned int u; } c;
    c.h2 = __float22bfloat162_rn(make_float2(lo, hi));   // v_cvt_pk_bf16_f32
    return c.u;
}

// DPP row_shr add chain {1,2,4,8}: lane l15==15 holds the 16-lane sum.
template <int CTRL>
static __device__ __forceinline__ float dpp_add(float v) {
    int x = __builtin_amdgcn_update_dpp(0, __float_as_int(v), CTRL, 0xF, 0xF, true);
    return v + __int_as_float(x);
}

// ---- mean(edge_attr) partial sums + split-K counter reset ------------------
__global__ __launch_bounds__(256) void k_ea_part(const float* __restrict__ ea,
                                                 float* __restrict__ part,
                                                 int* __restrict__ cnt) {
    __shared__ float s[256];
    int b = blockIdx.x, t = threadIdx.x;
    if (b == 0 && t < 64) cnt[t] = 0;      // re-arm split-K counters each call
    int col = t & 15, r0 = t >> 4;
    const float* base = ea + (size_t)b * 1024 * 16;
    float acc = 0.f;
    for (int r = r0; r < 1024; r += 16) acc += base[r * 16 + col];
    s[t] = acc; __syncthreads();
    for (int off = 128; off >= 16; off >>= 1) {
        if (t < off) s[t] += s[t + off];
        __syncthreads();
    }
    if (t < 16) part[b * 16 + t] = s[t];
}

// ---- fused GAT attention v8: xlr mini-GEMM + eeself + logits + softmax + agg
// All arithmetic bit-identical (canary 0.0078125). LDS 40512 B -> 4 blocks/CU.
__global__ __launch_bounds__(256, 4) void k_attn(const int* __restrict__ ei,
                                                 const float* __restrict__ ea,
                                                 const float* __restrict__ eapart,
                                                 const float* __restrict__ att,
                                                 const float* __restrict__ We,
                                                 const float* __restrict__ x,
                                                 const float* __restrict__ Wl,
                                                 const float* __restrict__ Wr,
                                                 const float* __restrict__ bg,
                                                 unsigned short* __restrict__ hb) {
    __shared__ float xlS[64][68];    // permuted cols, pitch 68
    __shared__ float xrS[64][68];
    __shared__ __align__(16) char uni[5376];   // ps | Bs[64][18] | lgS+srcS
    __shared__ float mean[16];
    __shared__ float eeselfS[64];

    float* lgS = (float*)uni;                              // [1088]
    unsigned int* srcSu = (unsigned int*)(uni + 4352);     // [256] packed bytes
    unsigned int* BsU = (unsigned int*)uni;                // Bs[col][kp] pitch18
    float (*ps)[16] = (float(*)[16])uni;                   // [16][16]

    int t = threadIdx.x;
    // XCD co-location: 4 head-blocks of graph g are g, g+256, g+512, g+768.
    int g = blockIdx.x & 255, h = blockIdx.x >> 8;
    int hc0 = h * 64;

    int wave = t >> 6, lane = t & 63;
    int q = lane >> 4, l15 = lane & 15, lk = lane >> 4;

    // ---- phase E: mean(ea) + eeself ----
    {
        int col = t & 15, bgi = t >> 4;
        float a = 0.f;
        #pragma unroll
        for (int i = 0; i < 16; ++i)
            a += eapart[(bgi + i * 16) * 16 + col];
        ps[bgi][col] = a;
        __syncthreads();
        if (t < 16) {
            float m = 0.f;
            #pragma unroll
            for (int i = 0; i < 16; ++i) m += ps[i][t];
            mean[t] = m * (1.f / (float)EDGES);
        }
        __syncthreads();
        if (t < 64) {
            float acc = 0.f;
            #pragma unroll
            for (int d = 0; d < 16; ++d) acc += mean[d] * We[d * 256 + hc0 + t];
            eeselfS[t] = acc;
        }
        __syncthreads();
    }

    // ---- phase X: xl|xr mini-GEMM ----
    {
        int wm = wave;
        const float* xrow = x + ((size_t)(g * 64 + wm * 16 + l15)) * 128 + lk * 8;
        floatx4 accL[4], accR[4];
        #pragma unroll
        for (int i = 0; i < 4; ++i) { accL[i] = (floatx4)(0.f); accR[i] = (floatx4)(0.f); }

        int bkp = t >> 4, bc4 = t & 15;

        for (int k0 = 0; k0 < 128; k0 += 32) {
            float4 xv0 = *(const float4*)(xrow + k0);
            float4 xv1 = *(const float4*)(xrow + k0 + 4);
            union { unsigned int u[4]; short8 v; } aa;
            aa.u[0] = packbf2(xv0.x, xv0.y);
            aa.u[1] = packbf2(xv0.z, xv0.w);
            aa.u[2] = packbf2(xv1.x, xv1.y);
            aa.u[3] = packbf2(xv1.z, xv1.w);
            short8 af = aa.v;

            #pragma unroll
            for (int side = 0; side < 2; ++side) {
                const float* Wsel = side ? Wr : Wl;
                __syncthreads();
                {
                    const float* wp = Wsel + (size_t)(k0 + 2 * bkp) * 256 + hc0 + bc4 * 4;
                    float4 r0 = *(const float4*)wp;
                    float4 r1 = *(const float4*)(wp + 256);
                    BsU[(bc4 * 4 + 0) * 18 + bkp] = packbf2(r0.x, r1.x);
                    BsU[(bc4 * 4 + 1) * 18 + bkp] = packbf2(r0.y, r1.y);
                    BsU[(bc4 * 4 + 2) * 18 + bkp] = packbf2(r0.z, r1.z);
                    BsU[(bc4 * 4 + 3) * 18 + bkp] = packbf2(r0.w, r1.w);
                }
                __syncthreads();
                #pragma unroll
                for (int ni = 0; ni < 4; ++ni) {
                    int nr = ni * 16 + l15;
                    union { uint2 u[2]; short8 v; } bb;
                    bb.u[0] = *(const uint2*)&BsU[nr * 18 + lk * 4];
                    bb.u[1] = *(const uint2*)&BsU[nr * 18 + lk * 4 + 2];
                    if (side == 0)
                        accL[ni] = __builtin_amdgcn_mfma_f32_16x16x32_bf16(af, bb.v, accL[ni], 0, 0, 0);
                    else
                        accR[ni] = __builtin_amdgcn_mfma_f32_16x16x32_bf16(af, bb.v, accR[ni], 0, 0, 0);
                }
            }
        }
        #pragma unroll
        for (int ni = 0; ni < 4; ++ni) {
            #pragma unroll
            for (int r = 0; r < 4; ++r) {
                int node = wm * 16 + lk * 4 + r;
                xlS[node][l15 * 4 + ni] = accL[ni][r];
                xrS[node][l15 * 4 + ni] = accR[ni][r];
            }
        }
    }
    __syncthreads();

    {   // stage local src indices, packed 4/uint
        int4 v = *(const int4*)(ei + (size_t)g * 1024 + t * 4);
        srcSu[t] = (unsigned int)(v.x & 63) | ((unsigned int)(v.y & 63) << 8) |
                   ((unsigned int)(v.z & 63) << 16) | ((unsigned int)(v.w & 63) << 24);
    }

    short8 wf[4];
    float  attv[4];
    #pragma unroll
    for (int nt = 0; nt < 4; ++nt) {
        attv[nt] = att[hc0 + nt * 16 + l15];
        if (q < 2) {
            const float* wp = We + (size_t)(q * 8) * 256 + hc0 + nt * 16 + l15;
            float w0 = wp[0*256], w1 = wp[1*256], w2 = wp[2*256], w3 = wp[3*256];
            float w4 = wp[4*256], w5 = wp[5*256], w6 = wp[6*256], w7 = wp[7*256];
            union { unsigned int u[4]; short8 v; } bb;
            bb.u[0] = packbf2(w0, w1);
            bb.u[1] = packbf2(w2, w3);
            bb.u[2] = packbf2(w4, w5);
            bb.u[3] = packbf2(w6, w7);
            wf[nt] = bb.v;
        } else {
            wf[nt] = (short8)0;
        }
    }
    __syncthreads();

    for (int b = wave; b < 16; b += 4) {
        short8 af[4];
        #pragma unroll
        for (int mt = 0; mt < 4; ++mt) {
            if (q < 2) {
                const float* ep = ea + ((size_t)(g * 1024 + b * 64 + mt * 16 + l15)) * 16 + q * 8;
                float4 v0 = *(const float4*)ep;
                float4 v1 = *(const float4*)(ep + 4);
                union { unsigned int u[4]; short8 v; } bb;
                bb.u[0] = packbf2(v0.x, v0.y);
                bb.u[1] = packbf2(v0.z, v0.w);
                bb.u[2] = packbf2(v1.x, v1.y);
                bb.u[3] = packbf2(v1.z, v1.w);
                af[mt] = bb.v;
            } else {
                af[mt] = (short8)0;
            }
        }
        floatx4 acc[4][4];
        #pragma unroll
        for (int mt = 0; mt < 4; ++mt)
            #pragma unroll
            for (int nt = 0; nt < 4; ++nt)
                acc[mt][nt] = __builtin_amdgcn_mfma_f32_16x16x32_bf16(af[mt], wf[nt], (floatx4)(0.f), 0, 0, 0);

        #pragma unroll
        for (int mt = 0; mt < 4; ++mt) {
            float4 xrv = *(const float4*)&xrS[b * 4 + mt][l15 * 4];
            unsigned int sw = srcSu[b * 16 + mt * 4 + q];
            int sr[4] = {(int)(sw & 255), (int)((sw >> 8) & 255),
                         (int)((sw >> 16) & 255), (int)(sw >> 24)};
            float lsum[4];
            #pragma unroll
            for (int r = 0; r < 4; ++r) {
                float4 xlv = *(const float4*)&xlS[sr[r]][l15 * 4];
                float f, acc_sum = 0.f;
                f = acc[mt][0][r] + xlv.x + xrv.x; f = fmaxf(f, NEG_SLOPE * f); acc_sum += f * attv[0];
                f = acc[mt][1][r] + xlv.y + xrv.y; f = fmaxf(f, NEG_SLOPE * f); acc_sum += f * attv[1];
                f = acc[mt][2][r] + xlv.z + xrv.z; f = fmaxf(f, NEG_SLOPE * f); acc_sum += f * attv[2];
                f = acc[mt][3][r] + xlv.w + xrv.w; f = fmaxf(f, NEG_SLOPE * f); acc_sum += f * attv[3];
                lsum[r] = acc_sum;
            }
            #pragma unroll
            for (int r = 0; r < 4; ++r) {
                float v = lsum[r];
                v = dpp_add<0x111>(v);
                v = dpp_add<0x112>(v);
                v = dpp_add<0x114>(v);
                v = dpp_add<0x118>(v);
                if (l15 == 15) lgS[b * 64 + mt * 16 + q * 4 + r] = v;
            }
        }
    }

    {   // self-loop batch
        int n = wave * 16 + l15;
        float sum = 0.f;
        #pragma unroll
        for (int i = 0; i < 4; ++i) {
            float4 ev = *(const float4*)&eeselfS[q * 16 + i * 4];
            float4 av = *(const float4*)(att + hc0 + q * 16 + i * 4);
            #pragma unroll
            for (int j = 0; j < 4; ++j) {
                int p = (i * 4 + j) * 4 + q;
                float e = (j == 0) ? ev.x : (j == 1) ? ev.y : (j == 2) ? ev.z : ev.w;
                float a = (j == 0) ? av.x : (j == 1) ? av.y : (j == 2) ? av.z : av.w;
                float f = xlS[n][p] + xrS[n][p] + e;
                f = fmaxf(f, NEG_SLOPE * f);
                sum += f * a;
            }
        }
        sum += __shfl_xor(sum, 16);
        sum += __shfl_xor(sum, 32);
        if (q == 0) lgS[1024 + n] = sum;
    }
    __syncthreads();

    if (t < 64) {
        float lg[17];
        #pragma unroll
        for (int j = 0; j < 16; ++j) lg[j] = lgS[t * 16 + j];
        lg[16] = lgS[1024 + t];
        float m = lg[0];
        #pragma unroll
        for (int j = 1; j < 17; ++j) m = fmaxf(m, lg[j]);
        float ex[17], ssum = 0.f;
        #pragma unroll
        for (int j = 0; j < 17; ++j) { ex[j] = __expf(lg[j] - m); ssum += ex[j]; }
        float inv = 1.f / (17.f * ssum);
        #pragma unroll
        for (int j = 0; j < 16; ++j) lgS[t * 16 + j] = ex[j] * inv;
        lgS[1024 + t] = ex[16] * inv;
    }
    __syncthreads();

    {   // aggregation
        int c = lane;
        int pc = (c & 15) * 4 + (c >> 4);
        float bgv = bg[hc0 + c];
        for (int n = wave * 16; n < wave * 16 + 16; ++n) {
            float4 al0 = *(const float4*)&lgS[n * 16];
            float4 al1 = *(const float4*)&lgS[n * 16 + 4];
            float4 al2 = *(const float4*)&lgS[n * 16 + 8];
            float4 al3 = *(const float4*)&lgS[n * 16 + 12];
            unsigned int w0 = srcSu[n * 4 + 0], w1 = srcSu[n * 4 + 1];
            unsigned int w2 = srcSu[n * 4 + 2], w3 = srcSu[n * 4 + 3];
            float a0 = lgS[1024 + n] * xlS[n][pc];
            float a1 = 0.f;
            a0 += al0.x * xlS[w0 & 255][pc];        a1 += al0.y * xlS[(w0 >> 8) & 255][pc];
            a0 += al0.z * xlS[(w0 >> 16) & 255][pc]; a1 += al0.w * xlS[w0 >> 24][pc];
            a0 += al1.x * xlS[w1 & 255][pc];        a1 += al1.y * xlS[(w1 >> 8) & 255][pc];
            a0 += al1.z * xlS[(w1 >> 16) & 255][pc]; a1 += al1.w * xlS[w1 >> 24][pc];
            a0 += al2.x * xlS[w2 & 255][pc];        a1 += al2.y * xlS[(w2 >> 8) & 255][pc];
            a0 += al2.z * xlS[(w2 >> 16) & 255][pc]; a1 += al2.w * xlS[w2 >> 24][pc];
            a0 += al3.x * xlS[w3 & 255][pc];        a1 += al3.y * xlS[(w3 >> 8) & 255][pc];
            a0 += al3.z * xlS[(w3 >> 16) & 255][pc]; a1 += al3.w * xlS[w3 >> 24][pc];
            float val = a0 + a1 + bgv;
            hb[((size_t)(g * 64 + n)) * 256 + hc0 + c] = f2bf(val);
        }
    }
}

// ---- big GEMM v9 + fused split-K reduction (last-arriver reduces) ----------
// Core loop identical to R12's v9. After epilogue: fence + agent-scope
// atomic on cnt[n0>>6]; the 8th arriver reduces its 256x64 output tile with
// k_reduce's exact summation order (bias, then s=0..7) -> bit-identical.
__global__ __launch_bounds__(256) void k_gemm(const unsigned short* __restrict__ hb,
                                              const float* __restrict__ W,
                                              float* __restrict__ parts,
                                              const float* __restrict__ lb,
                                              float* __restrict__ out,
                                              int* __restrict__ cnt) {
    __shared__ unsigned short As[3][256 * 32];
    __shared__ unsigned int   Bs[2][64][18];
    __shared__ int lastFlag;

    int t = threadIdx.x;
    int wave = t >> 6, lane = t & 63;
    int l15 = lane & 15, lk = lane >> 4;
    int bid = blockIdx.x;
    int s  = bid & 7;              // K-slice == XCD id
    int n0 = (bid >> 3) * 64;      // N-tile
    int kbase = s * 2048;

    floatx4 acc[4][4];
    #pragma unroll
    for (int i = 0; i < 4; ++i)
        #pragma unroll
        for (int j = 0; j < 4; ++j)
            acc[i][j] = (floatx4)(0.f);

    int gc = ((lane & 3) - ((lane >> 3) & 3)) & 3;
    const unsigned short* a_src =
        hb + (size_t)(wave * 64 + (lane >> 2)) * KDIM + kbase + gc * 8;
    int ap_off[4];
    #pragma unroll
    for (int mi = 0; mi < 4; ++mi)
        ap_off[mi] = (wave * 64 + mi * 16 + l15) * 32 + (((lk + (l15 >> 1)) & 3) * 8);

    int bkp = t >> 4;
    int bc8 = t & 15;
    const float* b_src = W + (size_t)(kbase + 2 * bkp) * 4096 + n0 + bc8 * 4;

    #define ISSUE_A(step, buf)                                                   \
        {                                                                        \
            const unsigned short* gp_ = a_src + (size_t)(step) * 32;             \
            _Pragma("unroll")                                                    \
            for (int i_ = 0; i_ < 4; ++i_) {                                     \
                __builtin_amdgcn_global_load_lds(                                \
                    (const __attribute__((address_space(1))) unsigned int*)      \
                        (gp_ + (size_t)i_ * 16 * KDIM),                          \
                    (__attribute__((address_space(3))) unsigned int*)            \
                        &As[buf][(wave * 64 + i_ * 16) * 32],                    \
                    16, 0, 0);                                                   \
            }                                                                    \
        }
    #define LOAD_B(step, r0, r1)                                                 \
        {                                                                        \
            const float* wp_ = b_src + (size_t)(step) * 32 * 4096;               \
            r0 = *(const float4*)wp_;                                            \
            r1 = *(const float4*)(wp_ + 4096);                                   \
        }
    #define WRITE_B(buf, r0, r1)                                                 \
        {                                                                        \
            Bs[buf][bc8 * 4 + 0][bkp] = packbf2(r0.x, r1.x);                     \
            Bs[buf][bc8 * 4 + 1][bkp] = packbf2(r0.y, r1.y);                     \
            Bs[buf][bc8 * 4 + 2][bkp] = packbf2(r0.z, r1.z);                     \
            Bs[buf][bc8 * 4 + 3][bkp] = packbf2(r0.w, r1.w);                     \
        }
    #define COMPUTE(abuf, bbuf)                                                  \
        {                                                                        \
            short8 a_[4], b_[4];                                                 \
            _Pragma("unroll")                                                    \
            for (int mi = 0; mi < 4; ++mi)                                       \
                a_[mi] = *(const short8*)&As[abuf][ap_off[mi]];                  \
            _Pragma("unroll")                                                    \
            for (int ni = 0; ni < 4; ++ni) {                                     \
                int nr_ = ni * 16 + l15;                                         \
                union { uint2 u[2]; short8 v; } bb_;                             \
                bb_.u[0] = *(const uint2*)&Bs[bbuf][nr_][lk * 4];                \
                bb_.u[1] = *(const uint2*)&Bs[bbuf][nr_][lk * 4 + 2];            \
                b_[ni] = bb_.v;                                                  \
            }                                                                    \
            __builtin_amdgcn_s_setprio(1);                                       \
            _Pragma("unroll")                                                    \
            for (int mi = 0; mi < 4; ++mi)                                       \
                _Pragma("unroll")                                                \
                for (int ni = 0; ni < 4; ++ni)                                   \
                    acc[mi][ni] = __builtin_amdgcn_mfma_f32_16x16x32_bf16(       \
                        a_[mi], b_[ni], acc[mi][ni], 0, 0, 0);                   \
            __builtin_amdgcn_s_setprio(0);                                       \
        }
    #define VMCNT(n) __builtin_amdgcn_sched_barrier(0);                          \
                     asm volatile("s_waitcnt vmcnt(" #n ")" ::: "memory");       \
                     __builtin_amdgcn_sched_barrier(0)
    #define LGKM0    asm volatile("s_waitcnt lgkmcnt(0)" ::: "memory");          \
                     __builtin_amdgcn_sched_barrier(0)
    #define STEP(jA, abufI, jB, ldS0, ldS1, cA, cB, wB, wS0, wS1, VM)            \
        ISSUE_A(jA, abufI);                                                      \
        LOAD_B(jB, ldS0, ldS1);                                                  \
        COMPUTE(cA, cB);                                                         \
        VMCNT(VM);                                                               \
        WRITE_B(wB, wS0, wS1);                                                   \
        LGKM0;                                                                   \
        __builtin_amdgcn_s_barrier();

    float4 s0a, s0b, s1a, s1b, s2a, s2b;

    // ---- prologue ----
    ISSUE_A(0, 0);
    LOAD_B(0, s0a, s0b);
    ISSUE_A(1, 1);
    LOAD_B(1, s1a, s1b);
    LOAD_B(2, s2a, s2b);
    VMCNT(8);
    WRITE_B(0, s0a, s0b);
    LGKM0;
    __builtin_amdgcn_s_barrier();

    // ---- steady: iters 0..59, unrolled by 6 ----
    for (int j = 0; j < 60; j += 6) {
        STEP(j + 2, 2, j + 3, s0a, s0b, 0, 0, 1, s1a, s1b, 8)
        STEP(j + 3, 0, j + 4, s1a, s1b, 1, 1, 0, s2a, s2b, 8)
        STEP(j + 4, 1, j + 5, s2a, s2b, 2, 0, 1, s0a, s0b, 8)
        STEP(j + 5, 2, j + 6, s0a, s0b, 0, 1, 0, s1a, s1b, 8)
        STEP(j + 6, 0, j + 7, s1a, s1b, 1, 0, 1, s2a, s2b, 8)
        STEP(j + 7, 1, j + 8, s2a, s2b, 2, 1, 0, s0a, s0b, 8)
    }
    // ---- iter 60 ----
    STEP(62, 2, 63, s0a, s0b, 0, 0, 1, s1a, s1b, 8)
    // ---- iter 61 (drain) ----
    ISSUE_A(63, 0);
    COMPUTE(1, 1);
    VMCNT(6);
    WRITE_B(0, s2a, s2b);
    LGKM0;
    __builtin_amdgcn_s_barrier();
    // ---- iter 62 ----
    COMPUTE(2, 0);
    VMCNT(4);
    WRITE_B(1, s0a, s0b);
    LGKM0;
    __builtin_amdgcn_s_barrier();
    // ---- iter 63 ----
    VMCNT(0);
    COMPUTE(0, 1);

    #undef ISSUE_A
    #undef LOAD_B
    #undef WRITE_B
    #undef COMPUTE
    #undef VMCNT
    #undef LGKM0
    #undef STEP

    float* dst = parts + (size_t)s * (256 * 4096);
    #pragma unroll
    for (int mi = 0; mi < 4; ++mi) {
        #pragma unroll
        for (int ni = 0; ni < 4; ++ni) {
            int col = n0 + ni * 16 + l15;
            #pragma unroll
            for (int r = 0; r < 4; ++r) {
                int row = wave * 64 + mi * 16 + lk * 4 + r;
                dst[(size_t)row * 4096 + col] = acc[mi][ni][r];
            }
        }
    }

    // ---- fused split-K reduction: last arriver for this n0 reduces ----
    __threadfence();   // make parts stores device-visible before counting
    if (t == 0) {
        int old = __hip_atomic_fetch_add(&cnt[n0 >> 6], 1,
                                         __ATOMIC_ACQ_REL, __HIP_MEMORY_SCOPE_AGENT);
        lastFlag = (old == 7);
    }
    __syncthreads();
    if (lastFlag) {
        int c = t & 63;
        int r0 = t >> 6;               // 0..3
        float bias = lb[n0 + c];       // == linb[idx & 4095]
        for (int r = r0; r < 256; r += 4) {
            size_t o = (size_t)r * 4096 + n0 + c;
            float v = bias;
            #pragma unroll
            for (int s2 = 0; s2 < 8; ++s2)
                v += parts[(size_t)s2 * (256 * 4096) + o];
            out[o] = v;
        }
    }
}

extern "C" void kernel_launch(void* const* d_in, const int* in_sizes, int n_in,
                              void* d_out, int out_size, void* d_ws, size_t ws_size,
                              hipStream_t stream) {
    (void)in_sizes; (void)n_in; (void)out_size; (void)ws_size;
    const float* x   = (const float*)d_in[0];
    const int*   ei  = (const int*)d_in[1];
    const float* ea  = (const float*)d_in[2];
    /* d_in[3] = batch (unused, fixed layout) */
    const float* Wl  = (const float*)d_in[4];
    const float* Wr  = (const float*)d_in[5];
    const float* We  = (const float*)d_in[6];
    const float* att = (const float*)d_in[7];
    const float* bg  = (const float*)d_in[8];
    const float* W   = (const float*)d_in[9];
    const float* lb  = (const float*)d_in[10];
    float* out = (float*)d_out;

    char* p = (char*)d_ws;
    unsigned short* hb  = (unsigned short*)p; p += 8388608;            // 16384x256 bf16
    float* parts        = (float*)p;          p += 33554432;           // 8x256x4096 f32
    float* eapart       = (float*)p;          p += 16384;              // 256x16
    int*   cnt          = (int*)p;            p += 1024;               // 64 counters

    k_ea_part<<<256,  256, 0, stream>>>(ea, eapart, cnt);
    k_attn   <<<1024, 256, 0, stream>>>(ei, ea, eapart, att, We, x, Wl, Wr, bg, hb);
    k_gemm   <<<512,  256, 0, stream>>>(hb, W, parts, lb, out, cnt);
}

// Round 15
// 157.891 us; speedup vs baseline: 1.5864x; 1.5864x over previous
//
#include <hip/hip_runtime.h>
#include <hip/hip_bf16.h>

// Problem constants (fixed by reference)
#define N_NODES   16384
#define DEG       16
#define EDGES     262144          // N_NODES*DEG
#define HC        256             // HEADS*OUT_C
#define KDIM      16384           // 64 nodes * 256 feat
#define NEG_SLOPE 0.2f

typedef __attribute__((ext_vector_type(8))) short short8;   // 8 bf16
typedef __attribute__((ext_vector_type(4))) float floatx4;

static __device__ __forceinline__ unsigned short f2bf(float f) {
    union { __hip_bfloat16 h; unsigned short u; } c;
    c.h = __float2bfloat16(f);          // RNE
    return c.u;
}
static __device__ __forceinline__ unsigned int packbf2(float lo, float hi) {
    union { __hip_bfloat162 h2; unsigned int u; } c;
    c.h2 = __float22bfloat162_rn(make_float2(lo, hi));   // v_cvt_pk_bf16_f32
    return c.u;
}

// DPP row_shr add chain {1,2,4,8}: lane l15==15 holds the 16-lane sum.
template <int CTRL>
static __device__ __forceinline__ float dpp_add(float v) {
    int x = __builtin_amdgcn_update_dpp(0, __float_as_int(v), CTRL, 0xF, 0xF, true);
    return v + __int_as_float(x);
}

// ---- mean(edge_attr) partial sums: 256 blocks x 1024 rows -----------------
__global__ __launch_bounds__(256) void k_ea_part(const float* __restrict__ ea,
                                                 float* __restrict__ part) {
    __shared__ float s[256];
    int b = blockIdx.x, t = threadIdx.x;
    int col = t & 15, r0 = t >> 4;
    const float* base = ea + (size_t)b * 1024 * 16;
    float acc = 0.f;
    for (int r = r0; r < 1024; r += 16) acc += base[r * 16 + col];
    s[t] = acc; __syncthreads();
    for (int off = 128; off >= 16; off >>= 1) {
        if (t < off) s[t] += s[t + off];
        __syncthreads();
    }
    if (t < 16) part[b * 16 + t] = s[t];
}

// ---- fused GAT attention v8: xlr mini-GEMM + eeself + logits + softmax + agg
// All arithmetic bit-identical (canary 0.0078125). LDS 40512 B -> 4 blocks/CU.
__global__ __launch_bounds__(256, 4) void k_attn(const int* __restrict__ ei,
                                                 const float* __restrict__ ea,
                                                 const float* __restrict__ eapart,
                                                 const float* __restrict__ att,
                                                 const float* __restrict__ We,
                                                 const float* __restrict__ x,
                                                 const float* __restrict__ Wl,
                                                 const float* __restrict__ Wr,
                                                 const float* __restrict__ bg,
                                                 unsigned short* __restrict__ hb) {
    __shared__ float xlS[64][68];    // permuted cols, pitch 68
    __shared__ float xrS[64][68];
    __shared__ __align__(16) char uni[5376];   // ps | Bs[64][18] | lgS+srcS
    __shared__ float mean[16];
    __shared__ float eeselfS[64];

    float* lgS = (float*)uni;                              // [1088]
    unsigned int* srcSu = (unsigned int*)(uni + 4352);     // [256] packed bytes
    unsigned int* BsU = (unsigned int*)uni;                // Bs[col][kp] pitch18
    float (*ps)[16] = (float(*)[16])uni;                   // [16][16]

    int t = threadIdx.x;
    // XCD co-location: 4 head-blocks of graph g are g, g+256, g+512, g+768.
    int g = blockIdx.x & 255, h = blockIdx.x >> 8;
    int hc0 = h * 64;

    int wave = t >> 6, lane = t & 63;
    int q = lane >> 4, l15 = lane & 15, lk = lane >> 4;

    // ---- phase E: mean(ea) + eeself ----
    {
        int col = t & 15, bgi = t >> 4;
        float a = 0.f;
        #pragma unroll
        for (int i = 0; i < 16; ++i)
            a += eapart[(bgi + i * 16) * 16 + col];
        ps[bgi][col] = a;
        __syncthreads();
        if (t < 16) {
            float m = 0.f;
            #pragma unroll
            for (int i = 0; i < 16; ++i) m += ps[i][t];
            mean[t] = m * (1.f / (float)EDGES);
        }
        __syncthreads();
        if (t < 64) {
            float acc = 0.f;
            #pragma unroll
            for (int d = 0; d < 16; ++d) acc += mean[d] * We[d * 256 + hc0 + t];
            eeselfS[t] = acc;
        }
        __syncthreads();
    }

    // ---- phase X: xl|xr mini-GEMM ----
    {
        int wm = wave;
        const float* xrow = x + ((size_t)(g * 64 + wm * 16 + l15)) * 128 + lk * 8;
        floatx4 accL[4], accR[4];
        #pragma unroll
        for (int i = 0; i < 4; ++i) { accL[i] = (floatx4)(0.f); accR[i] = (floatx4)(0.f); }

        int bkp = t >> 4, bc4 = t & 15;

        for (int k0 = 0; k0 < 128; k0 += 32) {
            float4 xv0 = *(const float4*)(xrow + k0);
            float4 xv1 = *(const float4*)(xrow + k0 + 4);
            union { unsigned int u[4]; short8 v; } aa;
            aa.u[0] = packbf2(xv0.x, xv0.y);
            aa.u[1] = packbf2(xv0.z, xv0.w);
            aa.u[2] = packbf2(xv1.x, xv1.y);
            aa.u[3] = packbf2(xv1.z, xv1.w);
            short8 af = aa.v;

            #pragma unroll
            for (int side = 0; side < 2; ++side) {
                const float* Wsel = side ? Wr : Wl;
                __syncthreads();
                {
                    const float* wp = Wsel + (size_t)(k0 + 2 * bkp) * 256 + hc0 + bc4 * 4;
                    float4 r0 = *(const float4*)wp;
                    float4 r1 = *(const float4*)(wp + 256);
                    BsU[(bc4 * 4 + 0) * 18 + bkp] = packbf2(r0.x, r1.x);
                    BsU[(bc4 * 4 + 1) * 18 + bkp] = packbf2(r0.y, r1.y);
                    BsU[(bc4 * 4 + 2) * 18 + bkp] = packbf2(r0.z, r1.z);
                    BsU[(bc4 * 4 + 3) * 18 + bkp] = packbf2(r0.w, r1.w);
                }
                __syncthreads();
                #pragma unroll
                for (int ni = 0; ni < 4; ++ni) {
                    int nr = ni * 16 + l15;
                    union { uint2 u[2]; short8 v; } bb;
                    bb.u[0] = *(const uint2*)&BsU[nr * 18 + lk * 4];
                    bb.u[1] = *(const uint2*)&BsU[nr * 18 + lk * 4 + 2];
                    if (side == 0)
                        accL[ni] = __builtin_amdgcn_mfma_f32_16x16x32_bf16(af, bb.v, accL[ni], 0, 0, 0);
                    else
                        accR[ni] = __builtin_amdgcn_mfma_f32_16x16x32_bf16(af, bb.v, accR[ni], 0, 0, 0);
                }
            }
        }
        #pragma unroll
        for (int ni = 0; ni < 4; ++ni) {
            #pragma unroll
            for (int r = 0; r < 4; ++r) {
                int node = wm * 16 + lk * 4 + r;
                xlS[node][l15 * 4 + ni] = accL[ni][r];
                xrS[node][l15 * 4 + ni] = accR[ni][r];
            }
        }
    }
    __syncthreads();

    {   // stage local src indices, packed 4/uint
        int4 v = *(const int4*)(ei + (size_t)g * 1024 + t * 4);
        srcSu[t] = (unsigned int)(v.x & 63) | ((unsigned int)(v.y & 63) << 8) |
                   ((unsigned int)(v.z & 63) << 16) | ((unsigned int)(v.w & 63) << 24);
    }

    short8 wf[4];
    float  attv[4];
    #pragma unroll
    for (int nt = 0; nt < 4; ++nt) {
        attv[nt] = att[hc0 + nt * 16 + l15];
        if (q < 2) {
            const float* wp = We + (size_t)(q * 8) * 256 + hc0 + nt * 16 + l15;
            float w0 = wp[0*256], w1 = wp[1*256], w2 = wp[2*256], w3 = wp[3*256];
            float w4 = wp[4*256], w5 = wp[5*256], w6 = wp[6*256], w7 = wp[7*256];
            union { unsigned int u[4]; short8 v; } bb;
            bb.u[0] = packbf2(w0, w1);
            bb.u[1] = packbf2(w2, w3);
            bb.u[2] = packbf2(w4, w5);
            bb.u[3] = packbf2(w6, w7);
            wf[nt] = bb.v;
        } else {
            wf[nt] = (short8)0;
        }
    }
    __syncthreads();

    for (int b = wave; b < 16; b += 4) {
        short8 af[4];
        #pragma unroll
        for (int mt = 0; mt < 4; ++mt) {
            if (q < 2) {
                const float* ep = ea + ((size_t)(g * 1024 + b * 64 + mt * 16 + l15)) * 16 + q * 8;
                float4 v0 = *(const float4*)ep;
                float4 v1 = *(const float4*)(ep + 4);
                union { unsigned int u[4]; short8 v; } bb;
                bb.u[0] = packbf2(v0.x, v0.y);
                bb.u[1] = packbf2(v0.z, v0.w);
                bb.u[2] = packbf2(v1.x, v1.y);
                bb.u[3] = packbf2(v1.z, v1.w);
                af[mt] = bb.v;
            } else {
                af[mt] = (short8)0;
            }
        }
        floatx4 acc[4][4];
        #pragma unroll
        for (int mt = 0; mt < 4; ++mt)
            #pragma unroll
            for (int nt = 0; nt < 4; ++nt)
                acc[mt][nt] = __builtin_amdgcn_mfma_f32_16x16x32_bf16(af[mt], wf[nt], (floatx4)(0.f), 0, 0, 0);

        #pragma unroll
        for (int mt = 0; mt < 4; ++mt) {
            float4 xrv = *(const float4*)&xrS[b * 4 + mt][l15 * 4];
            unsigned int sw = srcSu[b * 16 + mt * 4 + q];
            int sr[4] = {(int)(sw & 255), (int)((sw >> 8) & 255),
                         (int)((sw >> 16) & 255), (int)(sw >> 24)};
            float lsum[4];
            #pragma unroll
            for (int r = 0; r < 4; ++r) {
                float4 xlv = *(const float4*)&xlS[sr[r]][l15 * 4];
                float f, acc_sum = 0.f;
                f = acc[mt][0][r] + xlv.x + xrv.x; f = fmaxf(f, NEG_SLOPE * f); acc_sum += f * attv[0];
                f = acc[mt][1][r] + xlv.y + xrv.y; f = fmaxf(f, NEG_SLOPE * f); acc_sum += f * attv[1];
                f = acc[mt][2][r] + xlv.z + xrv.z; f = fmaxf(f, NEG_SLOPE * f); acc_sum += f * attv[2];
                f = acc[mt][3][r] + xlv.w + xrv.w; f = fmaxf(f, NEG_SLOPE * f); acc_sum += f * attv[3];
                lsum[r] = acc_sum;
            }
            #pragma unroll
            for (int r = 0; r < 4; ++r) {
                float v = lsum[r];
                v = dpp_add<0x111>(v);
                v = dpp_add<0x112>(v);
                v = dpp_add<0x114>(v);
                v = dpp_add<0x118>(v);
                if (l15 == 15) lgS[b * 64 + mt * 16 + q * 4 + r] = v;
            }
        }
    }

    {   // self-loop batch
        int n = wave * 16 + l15;
        float sum = 0.f;
        #pragma unroll
        for (int i = 0; i < 4; ++i) {
            float4 ev = *(const float4*)&eeselfS[q * 16 + i * 4];
            float4 av = *(const float4*)(att + hc0 + q * 16 + i * 4);
            #pragma unroll
            for (int j = 0; j < 4; ++j) {
                int p = (i * 4 + j) * 4 + q;
                float e = (j == 0) ? ev.x : (j == 1) ? ev.y : (j == 2) ? ev.z : ev.w;
                float a = (j == 0) ? av.x : (j == 1) ? av.y : (j == 2) ? av.z : av.w;
                float f = xlS[n][p] + xrS[n][p] + e;
                f = fmaxf(f, NEG_SLOPE * f);
                sum += f * a;
            }
        }
        sum += __shfl_xor(sum, 16);
        sum += __shfl_xor(sum, 32);
        if (q == 0) lgS[1024 + n] = sum;
    }
    __syncthreads();

    if (t < 64) {
        float lg[17];
        #pragma unroll
        for (int j = 0; j < 16; ++j) lg[j] = lgS[t * 16 + j];
        lg[16] = lgS[1024 + t];
        float m = lg[0];
        #pragma unroll
        for (int j = 1; j < 17; ++j) m = fmaxf(m, lg[j]);
        float ex[17], ssum = 0.f;
        #pragma unroll
        for (int j = 0; j < 17; ++j) { ex[j] = __expf(lg[j] - m); ssum += ex[j]; }
        float inv = 1.f / (17.f * ssum);
        #pragma unroll
        for (int j = 0; j < 16; ++j) lgS[t * 16 + j] = ex[j] * inv;
        lgS[1024 + t] = ex[16] * inv;
    }
    __syncthreads();

    {   // aggregation
        int c = lane;
        int pc = (c & 15) * 4 + (c >> 4);
        float bgv = bg[hc0 + c];
        for (int n = wave * 16; n < wave * 16 + 16; ++n) {
            float4 al0 = *(const float4*)&lgS[n * 16];
            float4 al1 = *(const float4*)&lgS[n * 16 + 4];
            float4 al2 = *(const float4*)&lgS[n * 16 + 8];
            float4 al3 = *(const float4*)&lgS[n * 16 + 12];
            unsigned int w0 = srcSu[n * 4 + 0], w1 = srcSu[n * 4 + 1];
            unsigned int w2 = srcSu[n * 4 + 2], w3 = srcSu[n * 4 + 3];
            float a0 = lgS[1024 + n] * xlS[n][pc];
            float a1 = 0.f;
            a0 += al0.x * xlS[w0 & 255][pc];        a1 += al0.y * xlS[(w0 >> 8) & 255][pc];
            a0 += al0.z * xlS[(w0 >> 16) & 255][pc]; a1 += al0.w * xlS[w0 >> 24][pc];
            a0 += al1.x * xlS[w1 & 255][pc];        a1 += al1.y * xlS[(w1 >> 8) & 255][pc];
            a0 += al1.z * xlS[(w1 >> 16) & 255][pc]; a1 += al1.w * xlS[w1 >> 24][pc];
            a0 += al2.x * xlS[w2 & 255][pc];        a1 += al2.y * xlS[(w2 >> 8) & 255][pc];
            a0 += al2.z * xlS[(w2 >> 16) & 255][pc]; a1 += al2.w * xlS[w2 >> 24][pc];
            a0 += al3.x * xlS[w3 & 255][pc];        a1 += al3.y * xlS[(w3 >> 8) & 255][pc];
            a0 += al3.z * xlS[(w3 >> 16) & 255][pc]; a1 += al3.w * xlS[w3 >> 24][pc];
            float val = a0 + a1 + bgv;
            hb[((size_t)(g * 64 + n)) * 256 + hc0 + c] = f2bf(val);
        }
    }
}

// ---- big GEMM v9: K-slice <-> XCD co-location; nt-stores for parts ---------
__global__ __launch_bounds__(256) void k_gemm(const unsigned short* __restrict__ hb,
                                              const float* __restrict__ W,
                                              float* __restrict__ parts) {
    __shared__ unsigned short As[3][256 * 32];
    __shared__ unsigned int   Bs[2][64][18];

    int t = threadIdx.x;
    int wave = t >> 6, lane = t & 63;
    int l15 = lane & 15, lk = lane >> 4;
    int bid = blockIdx.x;
    int s  = bid & 7;              // K-slice == XCD id
    int n0 = (bid >> 3) * 64;      // N-tile
    int kbase = s * 2048;

    floatx4 acc[4][4];
    #pragma unroll
    for (int i = 0; i < 4; ++i)
        #pragma unroll
        for (int j = 0; j < 4; ++j)
            acc[i][j] = (floatx4)(0.f);

    int gc = ((lane & 3) - ((lane >> 3) & 3)) & 3;
    const unsigned short* a_src =
        hb + (size_t)(wave * 64 + (lane >> 2)) * KDIM + kbase + gc * 8;
    int ap_off[4];
    #pragma unroll
    for (int mi = 0; mi < 4; ++mi)
        ap_off[mi] = (wave * 64 + mi * 16 + l15) * 32 + (((lk + (l15 >> 1)) & 3) * 8);

    int bkp = t >> 4;
    int bc8 = t & 15;
    const float* b_src = W + (size_t)(kbase + 2 * bkp) * 4096 + n0 + bc8 * 4;

    #define ISSUE_A(step, buf)                                                   \
        {                                                                        \
            const unsigned short* gp_ = a_src + (size_t)(step) * 32;             \
            _Pragma("unroll")                                                    \
            for (int i_ = 0; i_ < 4; ++i_) {                                     \
                __builtin_amdgcn_global_load_lds(                                \
                    (const __attribute__((address_space(1))) unsigned int*)      \
                        (gp_ + (size_t)i_ * 16 * KDIM),                          \
                    (__attribute__((address_space(3))) unsigned int*)            \
                        &As[buf][(wave * 64 + i_ * 16) * 32],                    \
                    16, 0, 0);                                                   \
            }                                                                    \
        }
    #define LOAD_B(step, r0, r1)                                                 \
        {                                                                        \
            const float* wp_ = b_src + (size_t)(step) * 32 * 4096;               \
            r0 = *(const float4*)wp_;                                            \
            r1 = *(const float4*)(wp_ + 4096);                                   \
        }
    #define WRITE_B(buf, r0, r1)                                                 \
        {                                                                        \
            Bs[buf][bc8 * 4 + 0][bkp] = packbf2(r0.x, r1.x);                     \
            Bs[buf][bc8 * 4 + 1][bkp] = packbf2(r0.y, r1.y);                     \
            Bs[buf][bc8 * 4 + 2][bkp] = packbf2(r0.z, r1.z);                     \
            Bs[buf][bc8 * 4 + 3][bkp] = packbf2(r0.w, r1.w);                     \
        }
    #define COMPUTE(abuf, bbuf)                                                  \
        {                                                                        \
            short8 a_[4], b_[4];                                                 \
            _Pragma("unroll")                                                    \
            for (int mi = 0; mi < 4; ++mi)                                       \
                a_[mi] = *(const short8*)&As[abuf][ap_off[mi]];                  \
            _Pragma("unroll")                                                    \
            for (int ni = 0; ni < 4; ++ni) {                                     \
                int nr_ = ni * 16 + l15;                                         \
                union { uint2 u[2]; short8 v; } bb_;                             \
                bb_.u[0] = *(const uint2*)&Bs[bbuf][nr_][lk * 4];                \
                bb_.u[1] = *(const uint2*)&Bs[bbuf][nr_][lk * 4 + 2];            \
                b_[ni] = bb_.v;                                                  \
            }                                                                    \
            __builtin_amdgcn_s_setprio(1);                                       \
            _Pragma("unroll")                                                    \
            for (int mi = 0; mi < 4; ++mi)                                       \
                _Pragma("unroll")                                                \
                for (int ni = 0; ni < 4; ++ni)                                   \
                    acc[mi][ni] = __builtin_amdgcn_mfma_f32_16x16x32_bf16(       \
                        a_[mi], b_[ni], acc[mi][ni], 0, 0, 0);                   \
            __builtin_amdgcn_s_setprio(0);                                       \
        }
    #define VMCNT(n) __builtin_amdgcn_sched_barrier(0);                          \
                     asm volatile("s_waitcnt vmcnt(" #n ")" ::: "memory");       \
                     __builtin_amdgcn_sched_barrier(0)
    #define LGKM0    asm volatile("s_waitcnt lgkmcnt(0)" ::: "memory");          \
                     __builtin_amdgcn_sched_barrier(0)
    #define STEP(jA, abufI, jB, ldS0, ldS1, cA, cB, wB, wS0, wS1, VM)            \
        ISSUE_A(jA, abufI);                                                      \
        LOAD_B(jB, ldS0, ldS1);                                                  \
        COMPUTE(cA, cB);                                                         \
        VMCNT(VM);                                                               \
        WRITE_B(wB, wS0, wS1);                                                   \
        LGKM0;                                                                   \
        __builtin_amdgcn_s_barrier();

    float4 s0a, s0b, s1a, s1b, s2a, s2b;

    // ---- prologue ----
    ISSUE_A(0, 0);
    LOAD_B(0, s0a, s0b);
    ISSUE_A(1, 1);
    LOAD_B(1, s1a, s1b);
    LOAD_B(2, s2a, s2b);
    VMCNT(8);
    WRITE_B(0, s0a, s0b);
    LGKM0;
    __builtin_amdgcn_s_barrier();

    // ---- steady: iters 0..59, unrolled by 6 ----
    for (int j = 0; j < 60; j += 6) {
        STEP(j + 2, 2, j + 3, s0a, s0b, 0, 0, 1, s1a, s1b, 8)
        STEP(j + 3, 0, j + 4, s1a, s1b, 1, 1, 0, s2a, s2b, 8)
        STEP(j + 4, 1, j + 5, s2a, s2b, 2, 0, 1, s0a, s0b, 8)
        STEP(j + 5, 2, j + 6, s0a, s0b, 0, 1, 0, s1a, s1b, 8)
        STEP(j + 6, 0, j + 7, s1a, s1b, 1, 0, 1, s2a, s2b, 8)
        STEP(j + 7, 1, j + 8, s2a, s2b, 2, 1, 0, s0a, s0b, 8)
    }
    // ---- iter 60 ----
    STEP(62, 2, 63, s0a, s0b, 0, 0, 1, s1a, s1b, 8)
    // ---- iter 61 (drain) ----
    ISSUE_A(63, 0);
    COMPUTE(1, 1);
    VMCNT(6);
    WRITE_B(0, s2a, s2b);
    LGKM0;
    __builtin_amdgcn_s_barrier();
    // ---- iter 62 ----
    COMPUTE(2, 0);
    VMCNT(4);
    WRITE_B(1, s0a, s0b);
    LGKM0;
    __builtin_amdgcn_s_barrier();
    // ---- iter 63 ----
    VMCNT(0);
    COMPUTE(0, 1);

    #undef ISSUE_A
    #undef LOAD_B
    #undef WRITE_B
    #undef COMPUTE
    #undef VMCNT
    #undef LGKM0
    #undef STEP

    float* dst = parts + (size_t)s * (256 * 4096);
    #pragma unroll
    for (int mi = 0; mi < 4; ++mi) {
        #pragma unroll
        for (int ni = 0; ni < 4; ++ni) {
            int col = n0 + ni * 16 + l15;
            #pragma unroll
            for (int r = 0; r < 4; ++r) {
                int row = wave * 64 + mi * 16 + lk * 4 + r;
                __builtin_nontemporal_store(acc[mi][ni][r],
                                            &dst[(size_t)row * 4096 + col]);
            }
        }
    }
}

// ---- reduce partials + bias -> d_out (nt streaming) ------------------------
__global__ __launch_bounds__(256) void k_reduce(const float* __restrict__ parts,
                                                const float* __restrict__ linb,
                                                float* __restrict__ out) {
    int idx = blockIdx.x * 256 + threadIdx.x;
    float v = linb[idx & 4095];
    #pragma unroll
    for (int s = 0; s < 8; ++s)
        v += __builtin_nontemporal_load(&parts[(size_t)s * (256 * 4096) + idx]);
    __builtin_nontemporal_store(v, &out[idx]);
}

extern "C" void kernel_launch(void* const* d_in, const int* in_sizes, int n_in,
                              void* d_out, int out_size, void* d_ws, size_t ws_size,
                              hipStream_t stream) {
    (void)in_sizes; (void)n_in; (void)out_size; (void)ws_size;
    const float* x   = (const float*)d_in[0];
    const int*   ei  = (const int*)d_in[1];
    const float* ea  = (const float*)d_in[2];
    /* d_in[3] = batch (unused, fixed layout) */
    const float* Wl  = (const float*)d_in[4];
    const float* Wr  = (const float*)d_in[5];
    const float* We  = (const float*)d_in[6];
    const float* att = (const float*)d_in[7];
    const float* bg  = (const float*)d_in[8];
    const float* W   = (const float*)d_in[9];
    const float* lb  = (const float*)d_in[10];
    float* out = (float*)d_out;

    char* p = (char*)d_ws;
    unsigned short* hb  = (unsigned short*)p; p += 8388608;            // 16384x256 bf16
    float* parts        = (float*)p;          p += 33554432;           // 8x256x4096 f32
    float* eapart       = (float*)p;          p += 16384;              // 256x16

    k_ea_part<<<256,  256, 0, stream>>>(ea, eapart);
    k_attn   <<<1024, 256, 0, stream>>>(ei, ea, eapart, att, We, x, Wl, Wr, bg, hb);
    k_gemm   <<<512,  256, 0, stream>>>(hb, W, parts);
    k_reduce <<<4096, 256, 0, stream>>>(parts, lb, out);
}

// Round 16
// 156.859 us; speedup vs baseline: 1.5968x; 1.0066x over previous
//
#include <hip/hip_runtime.h>
#include <hip/hip_bf16.h>

// Problem constants (fixed by reference)
#define N_NODES   16384
#define DEG       16
#define EDGES     262144          // N_NODES*DEG
#define HC        256             // HEADS*OUT_C
#define KDIM      16384           // 64 nodes * 256 feat
#define NEG_SLOPE 0.2f

typedef __attribute__((ext_vector_type(8))) short short8;   // 8 bf16
typedef __attribute__((ext_vector_type(4))) float floatx4;

static __device__ __forceinline__ unsigned short f2bf(float f) {
    union { __hip_bfloat16 h; unsigned short u; } c;
    c.h = __float2bfloat16(f);          // RNE
    return c.u;
}
static __device__ __forceinline__ unsigned int packbf2(float lo, float hi) {
    union { __hip_bfloat162 h2; unsigned int u; } c;
    c.h2 = __float22bfloat162_rn(make_float2(lo, hi));   // v_cvt_pk_bf16_f32
    return c.u;
}

// DPP row_shr add chain {1,2,4,8}: lane l15==15 holds the 16-lane sum.
template <int CTRL>
static __device__ __forceinline__ float dpp_add(float v) {
    int x = __builtin_amdgcn_update_dpp(0, __float_as_int(v), CTRL, 0xF, 0xF, true);
    return v + __int_as_float(x);
}

// ---- mean(edge_attr) partial sums: 256 blocks x 1024 rows -----------------
__global__ __launch_bounds__(256) void k_ea_part(const float* __restrict__ ea,
                                                 float* __restrict__ part) {
    __shared__ float s[256];
    int b = blockIdx.x, t = threadIdx.x;
    int col = t & 15, r0 = t >> 4;
    const float* base = ea + (size_t)b * 1024 * 16;
    float acc = 0.f;
    for (int r = r0; r < 1024; r += 16) acc += base[r * 16 + col];
    s[t] = acc; __syncthreads();
    for (int off = 128; off >= 16; off >>= 1) {
        if (t < off) s[t] += s[t + off];
        __syncthreads();
    }
    if (t < 16) part[b * 16 + t] = s[t];
}

// ---- fused GAT attention v9: pipelined phase-X W stages (T14) --------------
// All arithmetic bit-identical (canary 0.0078125). LDS 40512 B -> 4 blocks/CU.
__global__ __launch_bounds__(256, 4) void k_attn(const int* __restrict__ ei,
                                                 const float* __restrict__ ea,
                                                 const float* __restrict__ eapart,
                                                 const float* __restrict__ att,
                                                 const float* __restrict__ We,
                                                 const float* __restrict__ x,
                                                 const float* __restrict__ Wl,
                                                 const float* __restrict__ Wr,
                                                 const float* __restrict__ bg,
                                                 unsigned short* __restrict__ hb) {
    __shared__ float xlS[64][68];    // permuted cols, pitch 68
    __shared__ float xrS[64][68];
    __shared__ __align__(16) char uni[5376];   // ps | Bs[64][18] | lgS+srcS
    __shared__ float mean[16];
    __shared__ float eeselfS[64];

    float* lgS = (float*)uni;                              // [1088]
    unsigned int* srcSu = (unsigned int*)(uni + 4352);     // [256] packed bytes
    unsigned int* BsU = (unsigned int*)uni;                // Bs[col][kp] pitch18
    float (*ps)[16] = (float(*)[16])uni;                   // [16][16]

    int t = threadIdx.x;
    // XCD co-location: 4 head-blocks of graph g are g, g+256, g+512, g+768.
    int g = blockIdx.x & 255, h = blockIdx.x >> 8;
    int hc0 = h * 64;

    int wave = t >> 6, lane = t & 63;
    int q = lane >> 4, l15 = lane & 15, lk = lane >> 4;

    // ---- phase-X addressing + PRE-ISSUED stage-0 loads (hide under phase E)
    const float* xrow = x + ((size_t)(g * 64 + wave * 16 + l15)) * 128 + lk * 8;
    int bkp = t >> 4, bc4 = t & 15;

    #define LOADW_(side, k0, ra, rb)                                             \
        {                                                                        \
            const float* wp_ = ((side) ? Wr : Wl)                                \
                + (size_t)((k0) + 2 * bkp) * 256 + hc0 + bc4 * 4;                \
            ra = *(const float4*)wp_;                                            \
            rb = *(const float4*)(wp_ + 256);                                    \
        }
    #define LOADX_(k0) { xv0 = *(const float4*)(xrow + (k0));                    \
                         xv1 = *(const float4*)(xrow + (k0) + 4); }
    #define PACKX_() { union { unsigned int u[4]; short8 v; } aa_;               \
        aa_.u[0] = packbf2(xv0.x, xv0.y); aa_.u[1] = packbf2(xv0.z, xv0.w);      \
        aa_.u[2] = packbf2(xv1.x, xv1.y); aa_.u[3] = packbf2(xv1.z, xv1.w);      \
        af = aa_.v; }
    #define WRITEB_(ra, rb)                                                      \
        {                                                                        \
            BsU[(bc4 * 4 + 0) * 18 + bkp] = packbf2(ra.x, rb.x);                 \
            BsU[(bc4 * 4 + 1) * 18 + bkp] = packbf2(ra.y, rb.y);                 \
            BsU[(bc4 * 4 + 2) * 18 + bkp] = packbf2(ra.z, rb.z);                 \
            BsU[(bc4 * 4 + 3) * 18 + bkp] = packbf2(ra.w, rb.w);                 \
        }
    #define MFMAS_(accv)                                                         \
        {                                                                        \
            _Pragma("unroll")                                                    \
            for (int ni = 0; ni < 4; ++ni) {                                     \
                int nr = ni * 16 + l15;                                          \
                union { uint2 u[2]; short8 v; } bb_;                             \
                bb_.u[0] = *(const uint2*)&BsU[nr * 18 + lk * 4];                \
                bb_.u[1] = *(const uint2*)&BsU[nr * 18 + lk * 4 + 2];            \
                accv[ni] = __builtin_amdgcn_mfma_f32_16x16x32_bf16(              \
                    af, bb_.v, accv[ni], 0, 0, 0);                               \
            }                                                                    \
        }

    float4 wA0, wA1, wB0, wB1;   // ping-pong W stage regs
    float4 xv0, xv1;             // raw x for current k0-pair
    short8 af;

    LOADX_(0);                   // in flight across phase E
    LOADW_(0, 0, wA0, wA1);      // stage 0 (Wl, k0=0) in flight across phase E

    // ---- phase E: mean(ea) + eeself ----
    {
        int col = t & 15, bgi = t >> 4;
        float a = 0.f;
        #pragma unroll
        for (int i = 0; i < 16; ++i)
            a += eapart[(bgi + i * 16) * 16 + col];
        ps[bgi][col] = a;
        __syncthreads();
        if (t < 16) {
            float m = 0.f;
            #pragma unroll
            for (int i = 0; i < 16; ++i) m += ps[i][t];
            mean[t] = m * (1.f / (float)EDGES);
        }
        __syncthreads();
        if (t < 64) {
            float acc = 0.f;
            #pragma unroll
            for (int d = 0; d < 16; ++d) acc += mean[d] * We[d * 256 + hc0 + t];
            eeselfS[t] = acc;
        }
        __syncthreads();   // uni (ps) free
    }

    // ---- phase X: xl|xr mini-GEMM, 8 pipelined stages --------------------
    // stage p: (k0 = (p>>1)*32, side = p&1). LOADW for p+1 issued BEFORE the
    // barrier of p -> only stage 0's latency is exposed (and it hid under E).
    {
        floatx4 accL[4], accR[4];
        #pragma unroll
        for (int i = 0; i < 4; ++i) { accL[i] = (floatx4)(0.f); accR[i] = (floatx4)(0.f); }

        // stage 0: L, k0=0
        LOADW_(1, 0, wB0, wB1);
        __syncthreads(); WRITEB_(wA0, wA1); __syncthreads();
        PACKX_(); MFMAS_(accL);
        // stage 1: R, k0=0
        LOADW_(0, 32, wA0, wA1); LOADX_(32);
        __syncthreads(); WRITEB_(wB0, wB1); __syncthreads();
        MFMAS_(accR);
        // stage 2: L, k0=32
        LOADW_(1, 32, wB0, wB1);
        __syncthreads(); WRITEB_(wA0, wA1); __syncthreads();
        PACKX_(); MFMAS_(accL);
        // stage 3: R, k0=32
        LOADW_(0, 64, wA0, wA1); LOADX_(64);
        __syncthreads(); WRITEB_(wB0, wB1); __syncthreads();
        MFMAS_(accR);
        // stage 4: L, k0=64
        LOADW_(1, 64, wB0, wB1);
        __syncthreads(); WRITEB_(wA0, wA1); __syncthreads();
        PACKX_(); MFMAS_(accL);
        // stage 5: R, k0=64
        LOADW_(0, 96, wA0, wA1); LOADX_(96);
        __syncthreads(); WRITEB_(wB0, wB1); __syncthreads();
        MFMAS_(accR);
        // stage 6: L, k0=96
        LOADW_(1, 96, wB0, wB1);
        __syncthreads(); WRITEB_(wA0, wA1); __syncthreads();
        PACKX_(); MFMAS_(accL);
        // stage 7: R, k0=96
        __syncthreads(); WRITEB_(wB0, wB1); __syncthreads();
        MFMAS_(accR);

        // write to permuted LDS: logical col c = ni*16+l15 -> pc = l15*4 + ni
        #pragma unroll
        for (int ni = 0; ni < 4; ++ni) {
            #pragma unroll
            for (int r = 0; r < 4; ++r) {
                int node = wave * 16 + lk * 4 + r;
                xlS[node][l15 * 4 + ni] = accL[ni][r];
                xrS[node][l15 * 4 + ni] = accR[ni][r];
            }
        }
    }
    #undef LOADW_
    #undef LOADX_
    #undef PACKX_
    #undef WRITEB_
    #undef MFMAS_
    __syncthreads();   // xlS/xrS complete; Bs reads done -> uni reusable

    {   // stage local src indices, packed 4/uint
        int4 v = *(const int4*)(ei + (size_t)g * 1024 + t * 4);
        srcSu[t] = (unsigned int)(v.x & 63) | ((unsigned int)(v.y & 63) << 8) |
                   ((unsigned int)(v.z & 63) << 16) | ((unsigned int)(v.w & 63) << 24);
    }

    short8 wf[4];
    float  attv[4];
    #pragma unroll
    for (int nt = 0; nt < 4; ++nt) {
        attv[nt] = att[hc0 + nt * 16 + l15];
        if (q < 2) {
            const float* wp = We + (size_t)(q * 8) * 256 + hc0 + nt * 16 + l15;
            float w0 = wp[0*256], w1 = wp[1*256], w2 = wp[2*256], w3 = wp[3*256];
            float w4 = wp[4*256], w5 = wp[5*256], w6 = wp[6*256], w7 = wp[7*256];
            union { unsigned int u[4]; short8 v; } bb;
            bb.u[0] = packbf2(w0, w1);
            bb.u[1] = packbf2(w2, w3);
            bb.u[2] = packbf2(w4, w5);
            bb.u[3] = packbf2(w6, w7);
            wf[nt] = bb.v;
        } else {
            wf[nt] = (short8)0;
        }
    }
    __syncthreads();   // srcSu visible

    for (int b = wave; b < 16; b += 4) {
        short8 af2[4];
        #pragma unroll
        for (int mt = 0; mt < 4; ++mt) {
            if (q < 2) {
                const float* ep = ea + ((size_t)(g * 1024 + b * 64 + mt * 16 + l15)) * 16 + q * 8;
                float4 v0 = *(const float4*)ep;
                float4 v1 = *(const float4*)(ep + 4);
                union { unsigned int u[4]; short8 v; } bb;
                bb.u[0] = packbf2(v0.x, v0.y);
                bb.u[1] = packbf2(v0.z, v0.w);
                bb.u[2] = packbf2(v1.x, v1.y);
                bb.u[3] = packbf2(v1.z, v1.w);
                af2[mt] = bb.v;
            } else {
                af2[mt] = (short8)0;
            }
        }
        floatx4 acc[4][4];
        #pragma unroll
        for (int mt = 0; mt < 4; ++mt)
            #pragma unroll
            for (int nt = 0; nt < 4; ++nt)
                acc[mt][nt] = __builtin_amdgcn_mfma_f32_16x16x32_bf16(af2[mt], wf[nt], (floatx4)(0.f), 0, 0, 0);

        #pragma unroll
        for (int mt = 0; mt < 4; ++mt) {
            float4 xrv = *(const float4*)&xrS[b * 4 + mt][l15 * 4];
            unsigned int sw = srcSu[b * 16 + mt * 4 + q];
            int sr[4] = {(int)(sw & 255), (int)((sw >> 8) & 255),
                         (int)((sw >> 16) & 255), (int)(sw >> 24)};
            float lsum[4];
            #pragma unroll
            for (int r = 0; r < 4; ++r) {
                float4 xlv = *(const float4*)&xlS[sr[r]][l15 * 4];
                float f, acc_sum = 0.f;
                f = acc[mt][0][r] + xlv.x + xrv.x; f = fmaxf(f, NEG_SLOPE * f); acc_sum += f * attv[0];
                f = acc[mt][1][r] + xlv.y + xrv.y; f = fmaxf(f, NEG_SLOPE * f); acc_sum += f * attv[1];
                f = acc[mt][2][r] + xlv.z + xrv.z; f = fmaxf(f, NEG_SLOPE * f); acc_sum += f * attv[2];
                f = acc[mt][3][r] + xlv.w + xrv.w; f = fmaxf(f, NEG_SLOPE * f); acc_sum += f * attv[3];
                lsum[r] = acc_sum;
            }
            #pragma unroll
            for (int r = 0; r < 4; ++r) {
                float v = lsum[r];
                v = dpp_add<0x111>(v);
                v = dpp_add<0x112>(v);
                v = dpp_add<0x114>(v);
                v = dpp_add<0x118>(v);
                if (l15 == 15) lgS[b * 64 + mt * 16 + q * 4 + r] = v;
            }
        }
    }

    {   // self-loop batch
        int n = wave * 16 + l15;
        float sum = 0.f;
        #pragma unroll
        for (int i = 0; i < 4; ++i) {
            float4 ev = *(const float4*)&eeselfS[q * 16 + i * 4];
            float4 av = *(const float4*)(att + hc0 + q * 16 + i * 4);
            #pragma unroll
            for (int j = 0; j < 4; ++j) {
                int p = (i * 4 + j) * 4 + q;
                float e = (j == 0) ? ev.x : (j == 1) ? ev.y : (j == 2) ? ev.z : ev.w;
                float a = (j == 0) ? av.x : (j == 1) ? av.y : (j == 2) ? av.z : av.w;
                float f = xlS[n][p] + xrS[n][p] + e;
                f = fmaxf(f, NEG_SLOPE * f);
                sum += f * a;
            }
        }
        sum += __shfl_xor(sum, 16);
        sum += __shfl_xor(sum, 32);
        if (q == 0) lgS[1024 + n] = sum;
    }
    __syncthreads();

    if (t < 64) {
        float lg[17];
        #pragma unroll
        for (int j = 0; j < 16; ++j) lg[j] = lgS[t * 16 + j];
        lg[16] = lgS[1024 + t];
        float m = lg[0];
        #pragma unroll
        for (int j = 1; j < 17; ++j) m = fmaxf(m, lg[j]);
        float ex[17], ssum = 0.f;
        #pragma unroll
        for (int j = 0; j < 17; ++j) { ex[j] = __expf(lg[j] - m); ssum += ex[j]; }
        float inv = 1.f / (17.f * ssum);
        #pragma unroll
        for (int j = 0; j < 16; ++j) lgS[t * 16 + j] = ex[j] * inv;
        lgS[1024 + t] = ex[16] * inv;
    }
    __syncthreads();

    {   // aggregation
        int c = lane;
        int pc = (c & 15) * 4 + (c >> 4);
        float bgv = bg[hc0 + c];
        for (int n = wave * 16; n < wave * 16 + 16; ++n) {
            float4 al0 = *(const float4*)&lgS[n * 16];
            float4 al1 = *(const float4*)&lgS[n * 16 + 4];
            float4 al2 = *(const float4*)&lgS[n * 16 + 8];
            float4 al3 = *(const float4*)&lgS[n * 16 + 12];
            unsigned int w0 = srcSu[n * 4 + 0], w1 = srcSu[n * 4 + 1];
            unsigned int w2 = srcSu[n * 4 + 2], w3 = srcSu[n * 4 + 3];
            float a0 = lgS[1024 + n] * xlS[n][pc];
            float a1 = 0.f;
            a0 += al0.x * xlS[w0 & 255][pc];        a1 += al0.y * xlS[(w0 >> 8) & 255][pc];
            a0 += al0.z * xlS[(w0 >> 16) & 255][pc]; a1 += al0.w * xlS[w0 >> 24][pc];
            a0 += al1.x * xlS[w1 & 255][pc];        a1 += al1.y * xlS[(w1 >> 8) & 255][pc];
            a0 += al1.z * xlS[(w1 >> 16) & 255][pc]; a1 += al1.w * xlS[w1 >> 24][pc];
            a0 += al2.x * xlS[w2 & 255][pc];        a1 += al2.y * xlS[(w2 >> 8) & 255][pc];
            a0 += al2.z * xlS[(w2 >> 16) & 255][pc]; a1 += al2.w * xlS[w2 >> 24][pc];
            a0 += al3.x * xlS[w3 & 255][pc];        a1 += al3.y * xlS[(w3 >> 8) & 255][pc];
            a0 += al3.z * xlS[(w3 >> 16) & 255][pc]; a1 += al3.w * xlS[w3 >> 24][pc];
            float val = a0 + a1 + bgv;
            hb[((size_t)(g * 64 + n)) * 256 + hc0 + c] = f2bf(val);
        }
    }
}

// ---- big GEMM v9: K-slice <-> XCD co-location; nt-stores for parts ---------
__global__ __launch_bounds__(256) void k_gemm(const unsigned short* __restrict__ hb,
                                              const float* __restrict__ W,
                                              float* __restrict__ parts) {
    __shared__ unsigned short As[3][256 * 32];
    __shared__ unsigned int   Bs[2][64][18];

    int t = threadIdx.x;
    int wave = t >> 6, lane = t & 63;
    int l15 = lane & 15, lk = lane >> 4;
    int bid = blockIdx.x;
    int s  = bid & 7;              // K-slice == XCD id
    int n0 = (bid >> 3) * 64;      // N-tile
    int kbase = s * 2048;

    floatx4 acc[4][4];
    #pragma unroll
    for (int i = 0; i < 4; ++i)
        #pragma unroll
        for (int j = 0; j < 4; ++j)
            acc[i][j] = (floatx4)(0.f);

    int gc = ((lane & 3) - ((lane >> 3) & 3)) & 3;
    const unsigned short* a_src =
        hb + (size_t)(wave * 64 + (lane >> 2)) * KDIM + kbase + gc * 8;
    int ap_off[4];
    #pragma unroll
    for (int mi = 0; mi < 4; ++mi)
        ap_off[mi] = (wave * 64 + mi * 16 + l15) * 32 + (((lk + (l15 >> 1)) & 3) * 8);

    int bkp = t >> 4;
    int bc8 = t & 15;
    const float* b_src = W + (size_t)(kbase + 2 * bkp) * 4096 + n0 + bc8 * 4;

    #define ISSUE_A(step, buf)                                                   \
        {                                                                        \
            const unsigned short* gp_ = a_src + (size_t)(step) * 32;             \
            _Pragma("unroll")                                                    \
            for (int i_ = 0; i_ < 4; ++i_) {                                     \
                __builtin_amdgcn_global_load_lds(                                \
                    (const __attribute__((address_space(1))) unsigned int*)      \
                        (gp_ + (size_t)i_ * 16 * KDIM),                          \
                    (__attribute__((address_space(3))) unsigned int*)            \
                        &As[buf][(wave * 64 + i_ * 16) * 32],                    \
                    16, 0, 0);                                                   \
            }                                                                    \
        }
    #define LOAD_B(step, r0, r1)                                                 \
        {                                                                        \
            const float* wp_ = b_src + (size_t)(step) * 32 * 4096;               \
            r0 = *(const float4*)wp_;                                            \
            r1 = *(const float4*)(wp_ + 4096);                                   \
        }
    #define WRITE_B(buf, r0, r1)                                                 \
        {                                                                        \
            Bs[buf][bc8 * 4 + 0][bkp] = packbf2(r0.x, r1.x);                     \
            Bs[buf][bc8 * 4 + 1][bkp] = packbf2(r0.y, r1.y);                     \
            Bs[buf][bc8 * 4 + 2][bkp] = packbf2(r0.z, r1.z);                     \
            Bs[buf][bc8 * 4 + 3][bkp] = packbf2(r0.w, r1.w);                     \
        }
    #define COMPUTE(abuf, bbuf)                                                  \
        {                                                                        \
            short8 a_[4], b_[4];                                                 \
            _Pragma("unroll")                                                    \
            for (int mi = 0; mi < 4; ++mi)                                       \
                a_[mi] = *(const short8*)&As[abuf][ap_off[mi]];                  \
            _Pragma("unroll")                                                    \
            for (int ni = 0; ni < 4; ++ni) {                                     \
                int nr_ = ni * 16 + l15;                                         \
                union { uint2 u[2]; short8 v; } bb_;                             \
                bb_.u[0] = *(const uint2*)&Bs[bbuf][nr_][lk * 4];                \
                bb_.u[1] = *(const uint2*)&Bs[bbuf][nr_][lk * 4 + 2];            \
                b_[ni] = bb_.v;                                                  \
            }                                                                    \
            __builtin_amdgcn_s_setprio(1);                                       \
            _Pragma("unroll")                                                    \
            for (int mi = 0; mi < 4; ++mi)                                       \
                _Pragma("unroll")                                                \
                for (int ni = 0; ni < 4; ++ni)                                   \
                    acc[mi][ni] = __builtin_amdgcn_mfma_f32_16x16x32_bf16(       \
                        a_[mi], b_[ni], acc[mi][ni], 0, 0, 0);                   \
            __builtin_amdgcn_s_setprio(0);                                       \
        }
    #define VMCNT(n) __builtin_amdgcn_sched_barrier(0);                          \
                     asm volatile("s_waitcnt vmcnt(" #n ")" ::: "memory");       \
                     __builtin_amdgcn_sched_barrier(0)
    #define LGKM0    asm volatile("s_waitcnt lgkmcnt(0)" ::: "memory");          \
                     __builtin_amdgcn_sched_barrier(0)
    #define STEP(jA, abufI, jB, ldS0, ldS1, cA, cB, wB, wS0, wS1, VM)            \
        ISSUE_A(jA, abufI);                                                      \
        LOAD_B(jB, ldS0, ldS1);                                                  \
        COMPUTE(cA, cB);                                                         \
        VMCNT(VM);                                                               \
        WRITE_B(wB, wS0, wS1);                                                   \
        LGKM0;                                                                   \
        __builtin_amdgcn_s_barrier();

    float4 s0a, s0b, s1a, s1b, s2a, s2b;

    // ---- prologue ----
    ISSUE_A(0, 0);
    LOAD_B(0, s0a, s0b);
    ISSUE_A(1, 1);
    LOAD_B(1, s1a, s1b);
    LOAD_B(2, s2a, s2b);
    VMCNT(8);
    WRITE_B(0, s0a, s0b);
    LGKM0;
    __builtin_amdgcn_s_barrier();

    // ---- steady: iters 0..59, unrolled by 6 ----
    for (int j = 0; j < 60; j += 6) {
        STEP(j + 2, 2, j + 3, s0a, s0b, 0, 0, 1, s1a, s1b, 8)
        STEP(j + 3, 0, j + 4, s1a, s1b, 1, 1, 0, s2a, s2b, 8)
        STEP(j + 4, 1, j + 5, s2a, s2b, 2, 0, 1, s0a, s0b, 8)
        STEP(j + 5, 2, j + 6, s0a, s0b, 0, 1, 0, s1a, s1b, 8)
        STEP(j + 6, 0, j + 7, s1a, s1b, 1, 0, 1, s2a, s2b, 8)
        STEP(j + 7, 1, j + 8, s2a, s2b, 2, 1, 0, s0a, s0b, 8)
    }
    // ---- iter 60 ----
    STEP(62, 2, 63, s0a, s0b, 0, 0, 1, s1a, s1b, 8)
    // ---- iter 61 (drain) ----
    ISSUE_A(63, 0);
    COMPUTE(1, 1);
    VMCNT(6);
    WRITE_B(0, s2a, s2b);
    LGKM0;
    __builtin_amdgcn_s_barrier();
    // ---- iter 62 ----
    COMPUTE(2, 0);
    VMCNT(4);
    WRITE_B(1, s0a, s0b);
    LGKM0;
    __builtin_amdgcn_s_barrier();
    // ---- iter 63 ----
    VMCNT(0);
    COMPUTE(0, 1);

    #undef ISSUE_A
    #undef LOAD_B
    #undef WRITE_B
    #undef COMPUTE
    #undef VMCNT
    #undef LGKM0
    #undef STEP

    float* dst = parts + (size_t)s * (256 * 4096);
    #pragma unroll
    for (int mi = 0; mi < 4; ++mi) {
        #pragma unroll
        for (int ni = 0; ni < 4; ++ni) {
            int col = n0 + ni * 16 + l15;
            #pragma unroll
            for (int r = 0; r < 4; ++r) {
                int row = wave * 64 + mi * 16 + lk * 4 + r;
                __builtin_nontemporal_store(acc[mi][ni][r],
                                            &dst[(size_t)row * 4096 + col]);
            }
        }
    }
}

// ---- reduce partials + bias -> d_out (nt streaming) ------------------------
__global__ __launch_bounds__(256) void k_reduce(const float* __restrict__ parts,
                                                const float* __restrict__ linb,
                                                float* __restrict__ out) {
    int idx = blockIdx.x * 256 + threadIdx.x;
    float v = linb[idx & 4095];
    #pragma unroll
    for (int s = 0; s < 8; ++s)
        v += __builtin_nontemporal_load(&parts[(size_t)s * (256 * 4096) + idx]);
    __builtin_nontemporal_store(v, &out[idx]);
}

extern "C" void kernel_launch(void* const* d_in, const int* in_sizes, int n_in,
                              void* d_out, int out_size, void* d_ws, size_t ws_size,
                              hipStream_t stream) {
    (void)in_sizes; (void)n_in; (void)out_size; (void)ws_size;
    const float* x   = (const float*)d_in[0];
    const int*   ei  = (const int*)d_in[1];
    const float* ea  = (const float*)d_in[2];
    /* d_in[3] = batch (unused, fixed layout) */
    const float* Wl  = (const float*)d_in[4];
    const float* Wr  = (const float*)d_in[5];
    const float* We  = (const float*)d_in[6];
    const float* att = (const float*)d_in[7];
    const float* bg  = (const float*)d_in[8];
    const float* W   = (const float*)d_in[9];
    const float* lb  = (const float*)d_in[10];
    float* out = (float*)d_out;

    char* p = (char*)d_ws;
    unsigned short* hb  = (unsigned short*)p; p += 8388608;            // 16384x256 bf16
    float* parts        = (float*)p;          p += 33554432;           // 8x256x4096 f32
    float* eapart       = (float*)p;          p += 16384;              // 256x16

    k_ea_part<<<256,  256, 0, stream>>>(ea, eapart);
    k_attn   <<<1024, 256, 0, stream>>>(ei, ea, eapart, att, We, x, Wl, Wr, bg, hb);
    k_gemm   <<<512,  256, 0, stream>>>(hb, W, parts);
    k_reduce <<<4096, 256, 0, stream>>>(parts, lb, out);
}